// Round 6
// baseline (305.774 us; speedup 1.0000x reference)
//
#include <hip/hip_runtime.h>
#include <math.h>

// PCEN: per-(b,k) IIR smoother over T + pointwise pow compression.
// x: [B=32, C=1, K=128, T=8000] fp32.
// R9: lane = SEQUENCE, serial t-loop (scan eliminated). R3-R8 all ran at
// 81-88us with ~0.6 CU-cyc/elem of pure stall regardless of barriers/VALU/
// pipelining: the intra-sequence scan decomposition forces every wave
// through burst-load -> cross-lane scan (full load drain) -> apply ->
// burst-store phases. Meanwhile fillBufferAligned sustains 6.5 TB/s at 9%
// occupancy -- few waves are fine when the instruction stream is a long
// uniform load/compute/store stream. So: each lane owns one sequence and
// runs the NATURAL serial recurrence g = fma(a,g,x_t) down its own row
// (dwordx4 = 4 t per load; 64 lanes' lines fully consumed within 8 iters,
// so L1/L2 merge strided lane-streams to exact HBM traffic). Zero shfl /
// LDS / barriers / replay. Wave = 64 seqs x 1000-t segment (+480-sample
// truncated warmup, a^480 ~ 7e-6 -> out err ~2e-6). 64 seq-groups x 8
// t-segments = 512 single-wave blocks (2 waves/CU, fill-kernel regime),
// 10-deep rotating register prefetch (10 KB in flight per wave).
// Segment-0 init: g_pre = x0/s makes fma(a, g_pre, x0) = x0/s exactly
// (a + s = 1), so the loop body has no special cases at all.

constexpr int   T_LEN = 8000;
constexpr int   TSEG  = 1000;               // main t-span per wave
constexpr int   NSEG  = T_LEN / TSEG;       // 8
constexpr int   WARM  = 480;                // truncated history window
constexpr int   NPF   = 10;                 // prefetch depth (f32x4 iters)
constexpr int   WGRP  = WARM / 4 / NPF;     // 12 warmup groups
constexpr int   MGRP  = TSEG / 4 / NPF;     // 25 main groups
constexpr int   KDIM  = 128;
constexpr float EPS_F = 1e-6f;
constexpr float LOG2E = 1.4426950408889634f;

typedef float f32x4 __attribute__((ext_vector_type(4)));

__global__ __launch_bounds__(64) void pcen_kernel(
    const float* __restrict__ x,
    const float* __restrict__ log_s,
    const float* __restrict__ log_alpha,
    const float* __restrict__ log_delta,
    const float* __restrict__ log_r,
    float* __restrict__ out)
{
    const int lane = threadIdx.x;            // 0..63
    const int sg   = blockIdx.x >> 3;        // sequence group (nseq/64)
    const int ts   = blockIdx.x & (NSEG - 1);// t-segment 0..7
    const int seq  = (sg << 6) | lane;       // this lane's sequence
    const int k    = seq & (KDIM - 1);

    // ---- per-lane parameters (k varies per lane now) ----
    const float ls    = log_s[k];
    const float e_ns  = __builtin_amdgcn_exp2f(-ls * LOG2E);   // e^{-ls}
    const float inv_s = 1.0f + e_ns;                           // 1/s
    const float s     = __builtin_amdgcn_rcpf(inv_s);          // sigmoid
    const float a     = e_ns * s;                              // 1 - s
    const float alpha = __builtin_amdgcn_exp2f(log_alpha[k] * LOG2E);
    const float delta = __builtin_amdgcn_exp2f(log_delta[k] * LOG2E);
    const float r     = __builtin_amdgcn_exp2f(log_r[k] * LOG2E);
    const float dr    = __builtin_amdgcn_exp2f(r * log_delta[k] * LOG2E);

    const float* rowx = x   + (size_t)seq * T_LEN;             // per-lane row
    float*       rowo = out + (size_t)seq * T_LEN + ts * TSEG;

    const int tstart = ts ? ts * TSEG - WARM : 0;
    const int wgrp   = ts ? WGRP : 0;        // warmup groups (0 for seg 0)
    const int pfmax  = (T_LEN - 4 - tstart) >> 2;  // clamp prefetch in-row

    // g-space state (g = f/s). Segment-0 trick: g_pre = x0/s.
    float g = (ts == 0) ? rowx[0] * inv_s : 0.0f;

    // ---- prologue: fill the 10-deep rotating prefetch buffer ----
    f32x4 buf[NPF];
    #pragma unroll
    for (int i = 0; i < NPF; ++i)
        buf[i] = *(const f32x4*)(rowx + tstart + 4 * i);

    // ---- warmup: chain only (no output), truncated history ----
    for (int gI = 0; gI < wgrp; ++gI) {
        #pragma unroll
        for (int i = 0; i < NPF; ++i) {
            const int it = gI * NPF + i;
            const f32x4 xq = buf[i];
            int pfi = it + NPF; if (pfi > pfmax) pfi = pfmax;
            buf[i] = *(const f32x4*)(rowx + tstart + 4 * pfi);
            g = fmaf(a, g, xq[0]); g = fmaf(a, g, xq[1]);
            g = fmaf(a, g, xq[2]); g = fmaf(a, g, xq[3]);
        }
    }

    // ---- main: chain + PCEN pointwise + store, 4 t per iteration ----
    for (int gI = 0; gI < MGRP; ++gI) {
        #pragma unroll
        for (int i = 0; i < NPF; ++i) {
            const int mit = gI * NPF + i;            // main iter index
            const int it  = wgrp * NPF + mit;        // stream iter index
            const f32x4 xq = buf[i];
            int pfi = it + NPF; if (pfi > pfmax) pfi = pfmax;
            buf[i] = *(const f32x4*)(rowx + tstart + 4 * pfi);
            f32x4 o;
            #pragma unroll
            for (int e = 0; e < 4; ++e) {
                g = fmaf(a, g, xq[e]);               // serial recurrence
                const float lg  = __builtin_amdgcn_logf(fmaf(s, g, EPS_F));
                const float inv = __builtin_amdgcn_exp2f(-alpha * lg);  // (eps+f)^-a
                const float u   = fmaf(xq[e], inv, delta);
                o[e] = __builtin_amdgcn_exp2f(r * __builtin_amdgcn_logf(u)) - dr;
            }
            *(f32x4*)(rowo + 4 * mit) = o;
        }
    }
}

extern "C" void kernel_launch(void* const* d_in, const int* in_sizes, int n_in,
                              void* d_out, int out_size, void* d_ws, size_t ws_size,
                              hipStream_t stream) {
    const float* x         = (const float*)d_in[0];
    const float* log_s     = (const float*)d_in[1];
    const float* log_alpha = (const float*)d_in[2];
    const float* log_delta = (const float*)d_in[3];
    const float* log_r     = (const float*)d_in[4];
    float* out = (float*)d_out;

    const int nseq    = in_sizes[0] / T_LEN;     // 32*1*128 = 4096 sequences
    const int nblocks = (nseq / 64) * NSEG;      // 64 groups x 8 segs = 512
    pcen_kernel<<<nblocks, 64, 0, stream>>>(x, log_s, log_alpha, log_delta, log_r, out);
}

// Round 7
// 233.304 us; speedup vs baseline: 1.3106x; 1.3106x over previous
//
#include <hip/hip_runtime.h>
#include <math.h>

// PCEN: per-(b,k) IIR smoother over T + pointwise pow compression.
// x: [B=32, C=1, K=128, T=8000] fp32.
// R10: PERFECT COALESCING. Evidence across R5/R8/R9: HBM BW tracks lane
// address granularity (32KB stride -> 1.84 TB/s, 64B -> 2.29, 32B -> 2.55,
// 16B contiguous copy -> 6.3). All prior kernels gave each lane a
// contiguous elem CHUNK, so every VMEM instruction touched 32-64 cache
// lines using 16-32B of each -- a 2-4x per-line transaction tax that no
// barrier/pipeline change could fix (and compute is only ~10-15us of
// issue). Fix: thread owns exactly one float4 (16B); every load/store is
// 64 lanes x 16B = 1KB contiguous per instruction, the copy-ubench pattern.
// Block = 384 threads = one contiguous 1536-elem span: 512-elem truncated
// warmup (threads 0-127, a^512 ~ 3.4e-6 -> out err ~1e-7) + 1024 main
// elems (threads 128-383), processed by ONE unified 6-wave affine scan
// (local 4-elem map -> 64-lane shfl scan -> 6 carries via LDS -> 3-step
// redundant per-wave scan). Warmup re-reads are L3-hits (x=131MB < 256MB
// L3; R7: FETCH 64->69MB only). 4096 seqs x 8 blocks = 32768 blocks,
// 5 blocks/CU = 30 waves/CU. Absolute start: A=0 map at thread 128 of
// block 0 kills all upstream dependence; seg-0 warmup + tail threads are
// identity maps with clamped loads.
// Kept: g-space (g=f/s, one fma/elem; eps+f fuses), replay apply, raw
// v_exp/v_log/v_rcp builtins, cached stores.

constexpr int   T_LEN = 8000;
constexpr int   MAIN  = 1024;               // main elems per block
constexpr int   WARM  = 512;                // truncated-history window
constexpr int   NTH   = (MAIN + WARM) / 4;  // 384 threads (4 elems each)
constexpr int   NWAVE = NTH / 64;           // 6
constexpr int   WTH   = WARM / 4;           // 128 warmup threads
constexpr int   NBLK  = T_LEN / MAIN + 1;   // 8 blocks per sequence
constexpr int   KDIM  = 128;
constexpr float EPS_F = 1e-6f;
constexpr float LOG2E = 1.4426950408889634f;

typedef float f32x4 __attribute__((ext_vector_type(4)));

__global__ __launch_bounds__(NTH, 8) void pcen_kernel(
    const float* __restrict__ x,
    const float* __restrict__ log_s,
    const float* __restrict__ log_alpha,
    const float* __restrict__ log_delta,
    const float* __restrict__ log_r,
    float* __restrict__ out)
{
    __shared__ float wAs[NWAVE], wBs[NWAVE];

    const int tid  = threadIdx.x;
    const int lane = tid & 63;
    const int wave = tid >> 6;
    const int seq  = blockIdx.x >> 3;        // 8 blocks per sequence
    const int blk  = blockIdx.x & 7;
    const int k    = seq & (KDIM - 1);

    // ---- per-k parameters (block-uniform), raw v_exp_f32 ----
    const float ls    = log_s[k];
    const float e_ns  = __builtin_amdgcn_exp2f(-ls * LOG2E);   // e^{-ls}
    const float inv_s = 1.0f + e_ns;                           // 1/s
    const float s     = __builtin_amdgcn_rcpf(inv_s);          // sigmoid
    const float a     = e_ns * s;                              // 1 - s
    const float alpha = __builtin_amdgcn_exp2f(log_alpha[k] * LOG2E);
    const float delta = __builtin_amdgcn_exp2f(log_delta[k] * LOG2E);
    const float r     = __builtin_amdgcn_exp2f(log_r[k] * LOG2E);
    const float dr    = __builtin_amdgcn_exp2f(r * log_delta[k] * LOG2E);
    const float a2 = a * a, a4 = a2 * a2;

    const float* rowx = x + (size_t)seq * T_LEN;

    // this thread's 4 elements: contiguous span [blk*MAIN - WARM, blk*MAIN + MAIN)
    const int eb = blk * MAIN - WARM + tid * 4;       // may be <0 (blk 0) or >=T (blk 7)
    int lb = eb; if (lb < 0) lb = 0; if (lb > T_LEN - 4) lb = T_LEN - 4;
    const f32x4 xq = *(const f32x4*)(rowx + lb);      // 64 lanes x 16B contiguous

    const bool act      = (eb >= 0) && (eb + 4 <= T_LEN);
    const bool absstart = (blk == 0) && (tid == WTH); // owns elem 0

    // ---- local affine map over 4 elems (zero-init): g_out = A*g_in + B ----
    float A = 1.0f, B = 0.0f;                         // identity for inactive
    if (act) {
        float g;
        if (absstart) {
            g = xq[0] * inv_s;                        // f[0]=x[0] -> g=x[0]/s
            g = fmaf(a, g, xq[1]); g = fmaf(a, g, xq[2]); g = fmaf(a, g, xq[3]);
            A = 0.0f;                                 // kills upstream history
        } else {
            g = xq[0];                                // zero-init: a*0 + x0
            g = fmaf(a, g, xq[1]); g = fmaf(a, g, xq[2]); g = fmaf(a, g, xq[3]);
            A = a4;
        }
        B = g;
    }

    // ---- 64-lane inclusive scan (compose current∘previous) ----
    #pragma unroll
    for (int off = 1; off < 64; off <<= 1) {
        const float pA = __shfl_up(A, off, 64);
        const float pB = __shfl_up(B, off, 64);
        if (lane >= off) { B = fmaf(A, pB, B); A = A * pA; }
    }

    // ---- cross-wave: 6 carries through LDS, redundant 3-step scan per wave ----
    if (lane == 63) { wAs[wave] = A; wBs[wave] = B; }
    __syncthreads();
    float cA = 1.0f, cB = 0.0f;
    if (lane < NWAVE) { cA = wAs[lane]; cB = wBs[lane]; }
    #pragma unroll
    for (int off = 1; off < NWAVE; off <<= 1) {
        const float pA = __shfl_up(cA, off, 64);
        const float pB = __shfl_up(cB, off, 64);
        if (lane >= off) { cB = fmaf(cA, pB, cB); cA = cA * pA; }
    }
    const int   widx  = (wave > 0) ? wave - 1 : 0;
    const float vin_w = __shfl(cB, widx, 64);
    const float vin   = (wave == 0) ? 0.0f : vin_w;   // entering g for this wave

    // exclusive map within wave -> entering g for this thread's 4 elems
    float eA = __shfl_up(A, 1, 64);
    float eB = __shfl_up(B, 1, 64);
    if (lane == 0) { eA = 1.0f; eB = 0.0f; }
    const float fin = fmaf(eA, vin, eB);

    // ---- apply (main threads only): replay 4-elem chain; PCEN; store ----
    if (tid >= WTH && act) {
        float g = fin;
        f32x4 o;
        #pragma unroll
        for (int j = 0; j < 4; ++j) {
            const float xj = xq[j];
            if (j == 0 && absstart) g = xj * inv_s;   // absolute start
            else                    g = fmaf(a, g, xj);
            const float lg  = __builtin_amdgcn_logf(fmaf(s, g, EPS_F));
            const float inv = __builtin_amdgcn_exp2f(-alpha * lg);   // (eps+f)^-a
            const float u   = fmaf(xj, inv, delta);
            o[j] = __builtin_amdgcn_exp2f(r * __builtin_amdgcn_logf(u)) - dr;
        }
        *(f32x4*)(out + (size_t)seq * T_LEN + eb) = o; // 64 lanes x 16B contiguous
    }
}

extern "C" void kernel_launch(void* const* d_in, const int* in_sizes, int n_in,
                              void* d_out, int out_size, void* d_ws, size_t ws_size,
                              hipStream_t stream) {
    const float* x         = (const float*)d_in[0];
    const float* log_s     = (const float*)d_in[1];
    const float* log_alpha = (const float*)d_in[2];
    const float* log_delta = (const float*)d_in[3];
    const float* log_r     = (const float*)d_in[4];
    float* out = (float*)d_out;

    const int nseq    = in_sizes[0] / T_LEN;     // 32*1*128 = 4096 sequences
    const int nblocks = nseq * NBLK;             // 4096 * 8 = 32768
    pcen_kernel<<<nblocks, NTH, 0, stream>>>(x, log_s, log_alpha, log_delta, log_r, out);
}